// Round 8
// baseline (318.025 us; speedup 1.0000x reference)
//
#include <hip/hip_runtime.h>
#include <cstdint>

#define H 128
#define NGRAPH 256
#define ROWSTRIDE 68   // u32 per LDS tile row (64 data + 4 pad) -> 2-way max bank conflict
#define NPB 256        // nodes per bucket (bucket = dst >> 8); requires N <= 65536
#define CSR_CAP 6144   // LDS staging entries per bucket (mean ~4080, +32 sigma safe)

typedef __attribute__((ext_vector_type(8))) short short8;
typedef __attribute__((ext_vector_type(4))) float floatx4;

typedef unsigned short u16;
typedef unsigned int u32;

__device__ __forceinline__ u16 f2b(float f) {
    union { float f; u32 u; } v; v.f = f;
    u32 r = v.u + 0x7fffu + ((v.u >> 16) & 1u);
    return (u16)(r >> 16);
}
// bare u16 bf16 -> float (ONE shift)
__device__ __forceinline__ float b2f(u16 b) {
    union { u32 u; float f; } v; v.u = ((u32)b) << 16;
    return v.f;
}
// packed-pair helpers: take the full u32 holding two bf16
__device__ __forceinline__ float lo_f(u32 v) {
    union { u32 u; float f; } w; w.u = v << 16; return w.f;
}
__device__ __forceinline__ float hi_f(u32 v) {
    union { u32 u; float f; } w; w.u = v & 0xffff0000u; return w.f;
}

// ------------------------- fp32 -> bf16 convert -------------------------
__global__ void convert_kernel(const float* __restrict__ in, u16* __restrict__ out, int n4) {
    int i = blockIdx.x * blockDim.x + threadIdx.x;
    if (i < n4) {
        float4 v = *(const float4*)(in + (size_t)i * 4);
        u16 o[4] = { f2b(v.x), f2b(v.y), f2b(v.z), f2b(v.w) };
        *(uint2*)(out + (size_t)i * 4) = *(uint2*)o;
    }
}

// ------------------------- pack W into MFMA B-fragment order -------------------------
// packed[mat][ ((kc*8+nt)*64 + lane)*8 + j ] = W[mat][k=kc*32+(lane>>4)*8+j][n=nt*16+(lane&15)]
__global__ void pack_w_kernel(const float* __restrict__ W1, const float* __restrict__ W2,
                              u16* __restrict__ packed, int total) {
    int idx = blockIdx.x * blockDim.x + threadIdx.x;
    if (idx >= total) return;
    int mat = idx >> 14;           // /16384
    int pos = idx & 16383;
    int j    = pos & 7;
    int lane = (pos >> 3) & 63;
    int nt   = (pos >> 9) & 7;
    int kc   = pos >> 12;
    int k = kc * 32 + (lane >> 4) * 8 + j;
    int n = nt * 16 + (lane & 15);
    const float* src = (mat < 3) ? (W1 + (size_t)mat * H * H) : (W2 + (size_t)(mat - 3) * H * H);
    packed[idx] = f2b(src[(size_t)k * H + n]);
}

// ------------------------- CSR build: two-level bucket sort -------------------------
__global__ __launch_bounds__(256) void bucket_hist(const int* __restrict__ dstv,
                                                   int* __restrict__ bcnt, int E, int NB) {
    __shared__ int sh[256];
    int t = threadIdx.x;
    sh[t] = 0;
    __syncthreads();
    for (int e = blockIdx.x * 256 + t; e < E; e += gridDim.x * 256)
        atomicAdd(&sh[dstv[e] >> 8], 1);
    __syncthreads();
    if (t < NB && sh[t] > 0) atomicAdd(&bcnt[t], sh[t]);
}

__global__ void bucket_scan(const int* __restrict__ bcnt, int* __restrict__ boffs,
                            int* __restrict__ bcursor, int NB) {
    if (threadIdx.x == 0 && blockIdx.x == 0) {
        int run = 0;
        for (int i = 0; i < NB; ++i) { boffs[i] = run; bcursor[i] = run; run += bcnt[i]; }
        boffs[NB] = run;
    }
}

#define SCHUNK 4096
__global__ __launch_bounds__(256) void scatter_kernel(const int* __restrict__ src,
                                                      const int* __restrict__ dstv,
                                                      int* __restrict__ bcursor,
                                                      u32* __restrict__ stage, int E, int NB) {
    __shared__ int lcnt[256];
    __shared__ int lbase[256];
    int t = threadIdx.x;
    lcnt[t] = 0;
    __syncthreads();
    int base = blockIdx.x * SCHUNK;
    u32 pk[16];
    int bk[16];
#pragma unroll
    for (int i = 0; i < 16; ++i) {
        int idx = base + t + i * 256;
        bk[i] = -1;
        if (idx < E) {
            int s = src[idx];
            int d = dstv[idx];
            int b = d >> 8;
            pk[i] = (u32)s | ((u32)(d & 255) << 24);   // src < 2^24
            bk[i] = b;
            atomicAdd(&lcnt[b], 1);
        }
    }
    __syncthreads();
    if (t < NB && lcnt[t] > 0) lbase[t] = atomicAdd(&bcursor[t], lcnt[t]);
    __syncthreads();
    lcnt[t] = 0;
    __syncthreads();
#pragma unroll
    for (int i = 0; i < 16; ++i) {
        if (bk[i] >= 0) {
            int r = atomicAdd(&lcnt[bk[i]], 1);
            stage[(size_t)lbase[bk[i]] + r] = pk[i];
        }
    }
}

__global__ __launch_bounds__(256) void build_csr(const u32* __restrict__ stage,
                                                 const int* __restrict__ boffs,
                                                 int* __restrict__ offs, int* __restrict__ cols,
                                                 int N, int NB, int E) {
    __shared__ int cnt[256];
    __shared__ int cur[256];
    __shared__ int sA[256];
    __shared__ int sB[256];
    __shared__ int colstage[CSR_CAP];
    int b = blockIdx.x;
    int t = threadIdx.x;
    int lo = boffs[b], hi = boffs[b + 1];
    int sz = hi - lo;
    int nlo = b * NPB;
    cnt[t] = 0;
    __syncthreads();
    for (int i = t; i < sz; i += 256) atomicAdd(&cnt[stage[(size_t)lo + i] >> 24], 1);
    __syncthreads();
    sA[t] = cnt[t];
    __syncthreads();
    int* a = sA; int* bb = sB;
    for (int off = 1; off < 256; off <<= 1) {
        bb[t] = (t >= off) ? (a[t] + a[t - off]) : a[t];
        __syncthreads();
        int* tmp = a; a = bb; bb = tmp;
    }
    int excl = a[t] - cnt[t];
    if (nlo + t < N) offs[nlo + t] = lo + excl;
    if (b == 0 && t == 0) offs[N] = E;
    cur[t] = excl;
    __syncthreads();
    if (sz <= CSR_CAP) {
        for (int i = t; i < sz; i += 256) {
            u32 pk = stage[(size_t)lo + i];
            int r = atomicAdd(&cur[pk >> 24], 1);
            colstage[r] = (int)(pk & 0xFFFFFFu);
        }
        __syncthreads();
        for (int i = t; i < sz; i += 256) cols[(size_t)lo + i] = colstage[i];
    } else {
        for (int i = t; i < sz; i += 256) {
            u32 pk = stage[(size_t)lo + i];
            int r = atomicAdd(&cur[pk >> 24], 1);
            cols[(size_t)lo + r] = (int)(pk & 0xFFFFFFu);
        }
    }
}

// ------------------------- fused GIN layer -------------------------
// One block per 16-node tile: gather (CSR) -> LDS -> MFMA GEMM1(+bias,ReLU) -> LDS ->
// MFMA GEMM2(+bias,opt ReLU) -> store (or, for the last layer, fused dot with Wh -> y).
// Gather: each wave processes its 4 nodes SEQUENTIALLY with all 64 lanes on one row
// (lane = 2 feats) -> wave-uniform loop bounds (zero divergence), one coalesced 256B
// VMEM instruction per edge, unrolled x4 for MLP.
__global__ __launch_bounds__(256) void fused_layer(const u16* __restrict__ h,
                                                   u16* __restrict__ hout,
                                                   const int* __restrict__ offs,
                                                   const int* __restrict__ cols,
                                                   const u16* __restrict__ Wp1,
                                                   const u16* __restrict__ Wp2,
                                                   const float* __restrict__ bias1,
                                                   const float* __restrict__ bias2,
                                                   const float* __restrict__ eps, int layer,
                                                   int relu2, int lastLayer,
                                                   const float* __restrict__ Wh,
                                                   float* __restrict__ y, int N) {
    __shared__ u32 ldsA[16 * ROWSTRIDE];
    __shared__ u32 ldsB[16 * ROWSTRIDE];
    __shared__ float dacc[16];

    const int tid = threadIdx.x;
    const int wave = tid >> 6;
    const int lane = tid & 63;
    const int m = lane & 15;
    const int quad = lane >> 4;
    const int nt0 = wave * 2, nt1 = wave * 2 + 1;
    const int row0 = blockIdx.x * 16;

    const float scale = 1.0f + eps[layer];
    const u32* __restrict__ hp = (const u32*)h;

    // ---- gather: wave-sequential over its 4 nodes, 64 lanes per row ----
#pragma unroll
    for (int nn = 0; nn < 4; ++nn) {
        const int node = row0 + wave * 4 + nn;
        float ax = 0.f, ay = 0.f, bx = 0.f, by = 0.f;
        if (node < N) {
            u32 hv = hp[(size_t)node * 64 + lane];
            ax = scale * lo_f(hv);
            ay = scale * hi_f(hv);
            int beg = offs[node], end = offs[node + 1];
            int j = beg;
            for (; j + 4 <= end; j += 4) {
                int c0 = cols[j], c1 = cols[j + 1], c2 = cols[j + 2], c3 = cols[j + 3];
                u32 v0 = hp[(size_t)c0 * 64 + lane];
                u32 v1 = hp[(size_t)c1 * 64 + lane];
                u32 v2 = hp[(size_t)c2 * 64 + lane];
                u32 v3 = hp[(size_t)c3 * 64 + lane];
                ax += lo_f(v0) + lo_f(v2);
                ay += hi_f(v0) + hi_f(v2);
                bx += lo_f(v1) + lo_f(v3);
                by += hi_f(v1) + hi_f(v3);
            }
            for (; j < end; ++j) {
                u32 v = hp[(size_t)cols[j] * 64 + lane];
                ax += lo_f(v);
                ay += hi_f(v);
            }
            ax += bx;
            ay += by;
        }
        u16 p[2] = { f2b(ax), f2b(ay) };
        ldsA[(wave * 4 + nn) * ROWSTRIDE + lane] = *(u32*)p;
    }

    // B fragments (loaded in the gather's latency shadow)
    short8 B1f0[4], B1f1[4], B2f0[4], B2f1[4];
#pragma unroll
    for (int kc = 0; kc < 4; ++kc) {
        B1f0[kc] = *(const short8*)(Wp1 + ((size_t)(kc * 8 + nt0) * 64 + lane) * 8);
        B1f1[kc] = *(const short8*)(Wp1 + ((size_t)(kc * 8 + nt1) * 64 + lane) * 8);
        B2f0[kc] = *(const short8*)(Wp2 + ((size_t)(kc * 8 + nt0) * 64 + lane) * 8);
        B2f1[kc] = *(const short8*)(Wp2 + ((size_t)(kc * 8 + nt1) * 64 + lane) * 8);
    }
    const int cg0 = nt0 * 16 + m, cg1 = nt1 * 16 + m;
    const float b1v0 = bias1[cg0], b1v1 = bias1[cg1];
    const float b2v0 = bias2[cg0], b2v1 = bias2[cg1];
    __syncthreads();

    // ---- GEMM1: z1 = relu(z0 @ W1 + b1) ----
    {
        short8 a0 = *(const short8*)(&ldsA[m * ROWSTRIDE + 0 * 16 + quad * 4]);
        short8 a1 = *(const short8*)(&ldsA[m * ROWSTRIDE + 1 * 16 + quad * 4]);
        short8 a2 = *(const short8*)(&ldsA[m * ROWSTRIDE + 2 * 16 + quad * 4]);
        short8 a3 = *(const short8*)(&ldsA[m * ROWSTRIDE + 3 * 16 + quad * 4]);
        floatx4 acc0 = {0.f, 0.f, 0.f, 0.f};
        floatx4 acc1 = {0.f, 0.f, 0.f, 0.f};
        acc0 = __builtin_amdgcn_mfma_f32_16x16x32_bf16(a0, B1f0[0], acc0, 0, 0, 0);
        acc1 = __builtin_amdgcn_mfma_f32_16x16x32_bf16(a0, B1f1[0], acc1, 0, 0, 0);
        acc0 = __builtin_amdgcn_mfma_f32_16x16x32_bf16(a1, B1f0[1], acc0, 0, 0, 0);
        acc1 = __builtin_amdgcn_mfma_f32_16x16x32_bf16(a1, B1f1[1], acc1, 0, 0, 0);
        acc0 = __builtin_amdgcn_mfma_f32_16x16x32_bf16(a2, B1f0[2], acc0, 0, 0, 0);
        acc1 = __builtin_amdgcn_mfma_f32_16x16x32_bf16(a2, B1f1[2], acc1, 0, 0, 0);
        acc0 = __builtin_amdgcn_mfma_f32_16x16x32_bf16(a3, B1f0[3], acc0, 0, 0, 0);
        acc1 = __builtin_amdgcn_mfma_f32_16x16x32_bf16(a3, B1f1[3], acc1, 0, 0, 0);
        u16* lb = (u16*)ldsB;
#pragma unroll
        for (int i = 0; i < 4; ++i) {
            int rr = quad * 4 + i;
            lb[rr * (ROWSTRIDE * 2) + cg0] = f2b(fmaxf(acc0[i] + b1v0, 0.f));
            lb[rr * (ROWSTRIDE * 2) + cg1] = f2b(fmaxf(acc1[i] + b1v1, 0.f));
        }
        if (tid < 16) dacc[tid] = 0.f;
    }
    __syncthreads();

    // ---- GEMM2: z2 = (relu?)(z1 @ W2 + b2) ----
    {
        short8 a0 = *(const short8*)(&ldsB[m * ROWSTRIDE + 0 * 16 + quad * 4]);
        short8 a1 = *(const short8*)(&ldsB[m * ROWSTRIDE + 1 * 16 + quad * 4]);
        short8 a2 = *(const short8*)(&ldsB[m * ROWSTRIDE + 2 * 16 + quad * 4]);
        short8 a3 = *(const short8*)(&ldsB[m * ROWSTRIDE + 3 * 16 + quad * 4]);
        floatx4 acc0 = {0.f, 0.f, 0.f, 0.f};
        floatx4 acc1 = {0.f, 0.f, 0.f, 0.f};
        acc0 = __builtin_amdgcn_mfma_f32_16x16x32_bf16(a0, B2f0[0], acc0, 0, 0, 0);
        acc1 = __builtin_amdgcn_mfma_f32_16x16x32_bf16(a0, B2f1[0], acc1, 0, 0, 0);
        acc0 = __builtin_amdgcn_mfma_f32_16x16x32_bf16(a1, B2f0[1], acc0, 0, 0, 0);
        acc1 = __builtin_amdgcn_mfma_f32_16x16x32_bf16(a1, B2f1[1], acc1, 0, 0, 0);
        acc0 = __builtin_amdgcn_mfma_f32_16x16x32_bf16(a2, B2f0[2], acc0, 0, 0, 0);
        acc1 = __builtin_amdgcn_mfma_f32_16x16x32_bf16(a2, B2f1[2], acc1, 0, 0, 0);
        acc0 = __builtin_amdgcn_mfma_f32_16x16x32_bf16(a3, B2f0[3], acc0, 0, 0, 0);
        acc1 = __builtin_amdgcn_mfma_f32_16x16x32_bf16(a3, B2f1[3], acc1, 0, 0, 0);

        if (!lastLayer) {
            u16* la = (u16*)ldsA;
#pragma unroll
            for (int i = 0; i < 4; ++i) {
                int rr = quad * 4 + i;
                float v0 = acc0[i] + b2v0;
                float v1 = acc1[i] + b2v1;
                if (relu2) { v0 = fmaxf(v0, 0.f); v1 = fmaxf(v1, 0.f); }
                la[rr * (ROWSTRIDE * 2) + cg0] = f2b(v0);
                la[rr * (ROWSTRIDE * 2) + cg1] = f2b(v1);
            }
            __syncthreads();
            // coalesced store: each thread copies 16B
            int rr = tid >> 4;
            int s  = tid & 15;
            int grow = row0 + rr;
            if (grow < N) {
                uint4 v = *(uint4*)(&ldsA[rr * ROWSTRIDE + s * 4]);
                *(uint4*)(hout + (size_t)grow * H + s * 8) = v;
            }
        } else {
            // fused head: y[row] = sum_c bf16(z2[row][c]) * Wh[c]
            // (b2f = ONE left-shift of the bare u16 — round-trips through bf16 storage)
            const float wh0 = Wh[cg0], wh1 = Wh[cg1];
            float part[4];
#pragma unroll
            for (int i = 0; i < 4; ++i)
                part[i] = b2f(f2b(acc0[i] + b2v0)) * wh0 +
                          b2f(f2b(acc1[i] + b2v1)) * wh1;
            // reduce across the 16 lanes of each quad group (xor masks < 16 stay in-group)
#pragma unroll
            for (int off = 1; off < 16; off <<= 1)
#pragma unroll
                for (int i = 0; i < 4; ++i) part[i] += __shfl_xor(part[i], off, 64);
            if (m == 0) {
#pragma unroll
                for (int i = 0; i < 4; ++i) atomicAdd(&dacc[quad * 4 + i], part[i]);
            }
            __syncthreads();
            if (tid < 16 && row0 + tid < N) y[row0 + tid] = dacc[tid];
        }
    }
}

// ------------------------- per-graph mean via binary search on sorted batch -------------------------
__device__ __forceinline__ int lbound(const int* __restrict__ a, int n, int v) {
    int lo = 0, hi = n;
    while (lo < hi) { int mid = (lo + hi) >> 1; if (a[mid] < v) lo = mid + 1; else hi = mid; }
    return lo;
}

__global__ void seg_out_kernel(const float* __restrict__ y, const int* __restrict__ batch,
                               const float* __restrict__ bh, float* __restrict__ out, int N) {
    __shared__ float sh[256];
    int g = blockIdx.x;
    int lo = lbound(batch, N, g);
    int hi = lbound(batch, N, g + 1);
    float s = 0.f;
    for (int i = lo + threadIdx.x; i < hi; i += 256) s += y[i];
    sh[threadIdx.x] = s;
    __syncthreads();
    for (int off = 128; off > 0; off >>= 1) {
        if (threadIdx.x < off) sh[threadIdx.x] += sh[threadIdx.x + off];
        __syncthreads();
    }
    if (threadIdx.x == 0) {
        float cnt = (float)(hi - lo);
        out[g] = sh[0] / fmaxf(cnt, 1.0f) + bh[0];
    }
}

// ------------------------- launch -------------------------
extern "C" void kernel_launch(void* const* d_in, const int* in_sizes, int n_in,
                              void* d_out, int out_size, void* d_ws, size_t ws_size,
                              hipStream_t stream) {
    const float* x    = (const float*)d_in[0];
    const int*   eidx = (const int*)d_in[1];
    const int*   batch= (const int*)d_in[2];
    const float* W1   = (const float*)d_in[3];
    const float* b1   = (const float*)d_in[4];
    const float* W2   = (const float*)d_in[5];
    const float* b2   = (const float*)d_in[6];
    const float* eps  = (const float*)d_in[7];
    const float* Wh   = (const float*)d_in[8];
    const float* bh   = (const float*)d_in[9];

    const int N = in_sizes[0] / H;   // 50000
    const int E = in_sizes[1] / 2;   // 800000
    const int L = in_sizes[7];       // 3
    const int* src  = eidx;
    const int* dstv = eidx + E;
    float* out = (float*)d_out;

    const int NB = (N + NPB - 1) / NPB;   // 196 (<= 256 required)

    char* w = (char*)d_ws;
    u16* B0 = (u16*)w; w += (size_t)N * H * sizeof(u16);
    u16* B1 = (u16*)w; w += (size_t)N * H * sizeof(u16);
    u16* packedW = (u16*)w; w += (size_t)6 * H * H * sizeof(u16);
    float* y    = (float*)w; w += (size_t)N * sizeof(float);
    int* offs   = (int*)w;   w += (size_t)(N + 1) * sizeof(int);
    int* bcnt   = (int*)w;   w += 256 * sizeof(int);
    int* boffs  = (int*)w;   w += 257 * sizeof(int);
    int* bcursor= (int*)w;   w += 256 * sizeof(int);
    u32* stage  = (u32*)w;   w += (size_t)E * sizeof(u32);
    int* cols   = (int*)w;   w += (size_t)E * sizeof(int);

    hipMemsetAsync(bcnt, 0, 256 * sizeof(int), stream);

    // convert x -> bf16
    {
        int n4 = N * H / 4;
        convert_kernel<<<(n4 + 255) / 256, 256, 0, stream>>>(x, B0, n4);
    }
    // pack weights
    {
        int total = 6 * H * H;
        pack_w_kernel<<<(total + 255) / 256, 256, 0, stream>>>(W1, W2, packedW, total);
    }
    // CSR build (two-level bucket sort; no per-edge global atomics)
    bucket_hist<<<256, 256, 0, stream>>>(dstv, bcnt, E, NB);
    bucket_scan<<<1, 64, 0, stream>>>(bcnt, boffs, bcursor, NB);
    scatter_kernel<<<(E + SCHUNK - 1) / SCHUNK, 256, 0, stream>>>(src, dstv, bcursor, stage, E, NB);
    build_csr<<<NB, 256, 0, stream>>>(stage, boffs, offs, cols, N, NB, E);

    const int numTiles = (N + 15) / 16;   // 3125 -> one block per tile
    u16* bufs[2] = { B0, B1 };
    int cur = 0;
    for (int l = 0; l < L; ++l) {
        int nxt = cur ^ 1;
        int last = (l == L - 1) ? 1 : 0;
        fused_layer<<<numTiles, 256, 0, stream>>>(bufs[cur], bufs[nxt], offs, cols,
                                                  packedW + (size_t)l * H * H,
                                                  packedW + (size_t)(3 + l) * H * H,
                                                  b1 + (size_t)l * H, b2 + (size_t)l * H,
                                                  eps, l, (l < L - 1) ? 1 : 0, last,
                                                  Wh, y, N);
        cur = nxt;
    }

    seg_out_kernel<<<NGRAPH, 256, 0, stream>>>(y, batch, bh, out, N);
}

// Round 9
// 258.587 us; speedup vs baseline: 1.2299x; 1.2299x over previous
//
#include <hip/hip_runtime.h>
#include <cstdint>

#define H 128
#define NGRAPH 256
#define ROWSTRIDE 68   // u32 per LDS tile row (64 data + 4 pad) -> 2-way max bank conflict
#define NPB 256        // nodes per bucket (bucket = dst >> 8); requires N <= 65536
#define CSR_CAP 6144   // LDS staging entries per bucket (mean ~4080, +32 sigma safe)

typedef __attribute__((ext_vector_type(8))) short short8;
typedef __attribute__((ext_vector_type(4))) float floatx4;

typedef unsigned short u16;
typedef unsigned int u32;

__device__ __forceinline__ u16 f2b(float f) {
    union { float f; u32 u; } v; v.f = f;
    u32 r = v.u + 0x7fffu + ((v.u >> 16) & 1u);
    return (u16)(r >> 16);
}
// bare u16 bf16 -> float (ONE shift)
__device__ __forceinline__ float b2f(u16 b) {
    union { u32 u; float f; } v; v.u = ((u32)b) << 16;
    return v.f;
}
// packed-pair helpers: take the full u32 holding two bf16
__device__ __forceinline__ float lo_f(u32 v) {
    union { u32 u; float f; } w; w.u = v << 16; return w.f;
}
__device__ __forceinline__ float hi_f(u32 v) {
    union { u32 u; float f; } w; w.u = v & 0xffff0000u; return w.f;
}

// ------------------------- fp32 -> bf16 convert -------------------------
__global__ void convert_kernel(const float* __restrict__ in, u16* __restrict__ out, int n4) {
    int i = blockIdx.x * blockDim.x + threadIdx.x;
    if (i < n4) {
        float4 v = *(const float4*)(in + (size_t)i * 4);
        u16 o[4] = { f2b(v.x), f2b(v.y), f2b(v.z), f2b(v.w) };
        *(uint2*)(out + (size_t)i * 4) = *(uint2*)o;
    }
}

// ------------------------- pack W into MFMA B-fragment order -------------------------
// packed[mat][ ((kc*8+nt)*64 + lane)*8 + j ] = W[mat][k=kc*32+(lane>>4)*8+j][n=nt*16+(lane&15)]
__global__ void pack_w_kernel(const float* __restrict__ W1, const float* __restrict__ W2,
                              u16* __restrict__ packed, int total) {
    int idx = blockIdx.x * blockDim.x + threadIdx.x;
    if (idx >= total) return;
    int mat = idx >> 14;           // /16384
    int pos = idx & 16383;
    int j    = pos & 7;
    int lane = (pos >> 3) & 63;
    int nt   = (pos >> 9) & 7;
    int kc   = pos >> 12;
    int k = kc * 32 + (lane >> 4) * 8 + j;
    int n = nt * 16 + (lane & 15);
    const float* src = (mat < 3) ? (W1 + (size_t)mat * H * H) : (W2 + (size_t)(mat - 3) * H * H);
    packed[idx] = f2b(src[(size_t)k * H + n]);
}

// ------------------------- CSR build: two-level bucket sort -------------------------
__global__ __launch_bounds__(256) void bucket_hist(const int* __restrict__ dstv,
                                                   int* __restrict__ bcnt, int E, int NB) {
    __shared__ int sh[256];
    int t = threadIdx.x;
    sh[t] = 0;
    __syncthreads();
    for (int e = blockIdx.x * 256 + t; e < E; e += gridDim.x * 256)
        atomicAdd(&sh[dstv[e] >> 8], 1);
    __syncthreads();
    if (t < NB && sh[t] > 0) atomicAdd(&bcnt[t], sh[t]);
}

__global__ void bucket_scan(const int* __restrict__ bcnt, int* __restrict__ boffs,
                            int* __restrict__ bcursor, int NB) {
    if (threadIdx.x == 0 && blockIdx.x == 0) {
        int run = 0;
        for (int i = 0; i < NB; ++i) { boffs[i] = run; bcursor[i] = run; run += bcnt[i]; }
        boffs[NB] = run;
    }
}

#define SCHUNK 4096
__global__ __launch_bounds__(256) void scatter_kernel(const int* __restrict__ src,
                                                      const int* __restrict__ dstv,
                                                      int* __restrict__ bcursor,
                                                      u32* __restrict__ stage, int E, int NB) {
    __shared__ int lcnt[256];
    __shared__ int lbase[256];
    int t = threadIdx.x;
    lcnt[t] = 0;
    __syncthreads();
    int base = blockIdx.x * SCHUNK;
    u32 pk[16];
    int bk[16];
#pragma unroll
    for (int i = 0; i < 16; ++i) {
        int idx = base + t + i * 256;
        bk[i] = -1;
        if (idx < E) {
            int s = src[idx];
            int d = dstv[idx];
            int b = d >> 8;
            pk[i] = (u32)s | ((u32)(d & 255) << 24);   // src < 2^24
            bk[i] = b;
            atomicAdd(&lcnt[b], 1);
        }
    }
    __syncthreads();
    if (t < NB && lcnt[t] > 0) lbase[t] = atomicAdd(&bcursor[t], lcnt[t]);
    __syncthreads();
    lcnt[t] = 0;
    __syncthreads();
#pragma unroll
    for (int i = 0; i < 16; ++i) {
        if (bk[i] >= 0) {
            int r = atomicAdd(&lcnt[bk[i]], 1);
            stage[(size_t)lbase[bk[i]] + r] = pk[i];
        }
    }
}

__global__ __launch_bounds__(256) void build_csr(const u32* __restrict__ stage,
                                                 const int* __restrict__ boffs,
                                                 int* __restrict__ offs, int* __restrict__ cols,
                                                 int N, int NB, int E) {
    __shared__ int cnt[256];
    __shared__ int cur[256];
    __shared__ int sA[256];
    __shared__ int sB[256];
    __shared__ int colstage[CSR_CAP];
    int b = blockIdx.x;
    int t = threadIdx.x;
    int lo = boffs[b], hi = boffs[b + 1];
    int sz = hi - lo;
    int nlo = b * NPB;
    cnt[t] = 0;
    __syncthreads();
    for (int i = t; i < sz; i += 256) atomicAdd(&cnt[stage[(size_t)lo + i] >> 24], 1);
    __syncthreads();
    sA[t] = cnt[t];
    __syncthreads();
    int* a = sA; int* bb = sB;
    for (int off = 1; off < 256; off <<= 1) {
        bb[t] = (t >= off) ? (a[t] + a[t - off]) : a[t];
        __syncthreads();
        int* tmp = a; a = bb; bb = tmp;
    }
    int excl = a[t] - cnt[t];
    if (nlo + t < N) offs[nlo + t] = lo + excl;
    if (b == 0 && t == 0) offs[N] = E;
    cur[t] = excl;
    __syncthreads();
    if (sz <= CSR_CAP) {
        for (int i = t; i < sz; i += 256) {
            u32 pk = stage[(size_t)lo + i];
            int r = atomicAdd(&cur[pk >> 24], 1);
            colstage[r] = (int)(pk & 0xFFFFFFu);
        }
        __syncthreads();
        for (int i = t; i < sz; i += 256) cols[(size_t)lo + i] = colstage[i];
    } else {
        for (int i = t; i < sz; i += 256) {
            u32 pk = stage[(size_t)lo + i];
            int r = atomicAdd(&cur[pk >> 24], 1);
            cols[(size_t)lo + r] = (int)(pk & 0xFFFFFFu);
        }
    }
}

// ------------------------- fused GIN layer -------------------------
// One block per 16-node tile: gather (CSR) -> LDS -> MFMA GEMM1(+bias,ReLU) -> LDS ->
// MFMA GEMM2(+bias,opt ReLU) -> store (or, last layer, fused dot with Wh -> y).
// Gather: GROUP-PARALLEL (each 16-lane group owns one node, 4 nodes per wave in
// parallel) with edge-loop unroll x4 -> 16 independent row-loads in flight per wave.
// [R8 lesson: wave-sequential gather (1 coalesced load/edge, zero divergence) REGRESSED
//  59 vs 45 µs — sequential dynamic loops kill memory-level parallelism. MLP > exec-mask.]
__global__ __launch_bounds__(256) void fused_layer(const u16* __restrict__ h,
                                                   u16* __restrict__ hout,
                                                   const int* __restrict__ offs,
                                                   const int* __restrict__ cols,
                                                   const u16* __restrict__ Wp1,
                                                   const u16* __restrict__ Wp2,
                                                   const float* __restrict__ bias1,
                                                   const float* __restrict__ bias2,
                                                   const float* __restrict__ eps, int layer,
                                                   int relu2, int lastLayer,
                                                   const float* __restrict__ Wh,
                                                   float* __restrict__ y, int N) {
    __shared__ u32 ldsA[16 * ROWSTRIDE];
    __shared__ u32 ldsB[16 * ROWSTRIDE];
    __shared__ float dacc[16];

    const int tid = threadIdx.x;
    const int wave = tid >> 6;
    const int lane = tid & 63;
    const int m = lane & 15;
    const int quad = lane >> 4;
    const int nt0 = wave * 2, nt1 = wave * 2 + 1;
    const int row0 = blockIdx.x * 16;

    const float scale = 1.0f + eps[layer];
    const u32* __restrict__ hp = (const u32*)h;

    // ---- gather: group-parallel; lane covers 4 u32 (8 feats) of its group's node ----
    {
        const int nid = wave * 4 + quad;       // 0..15
        const int node = row0 + nid;
        float a[8];
#pragma unroll
        for (int i = 0; i < 8; ++i) a[i] = 0.f;
        if (node < N) {
#pragma unroll
            for (int i = 0; i < 4; ++i) {
                u32 v = hp[(size_t)node * 64 + m + 16 * i];
                a[2 * i]     = scale * lo_f(v);
                a[2 * i + 1] = scale * hi_f(v);
            }
            int beg = offs[node], end = offs[node + 1];
            int j = beg;
            for (; j + 4 <= end; j += 4) {
                int c0 = cols[j], c1 = cols[j + 1], c2 = cols[j + 2], c3 = cols[j + 3];
                u32 v0[4], v1[4], v2[4], v3[4];
#pragma unroll
                for (int i = 0; i < 4; ++i) v0[i] = hp[(size_t)c0 * 64 + m + 16 * i];
#pragma unroll
                for (int i = 0; i < 4; ++i) v1[i] = hp[(size_t)c1 * 64 + m + 16 * i];
#pragma unroll
                for (int i = 0; i < 4; ++i) v2[i] = hp[(size_t)c2 * 64 + m + 16 * i];
#pragma unroll
                for (int i = 0; i < 4; ++i) v3[i] = hp[(size_t)c3 * 64 + m + 16 * i];
#pragma unroll
                for (int i = 0; i < 4; ++i) {
                    a[2 * i]     += (lo_f(v0[i]) + lo_f(v1[i])) + (lo_f(v2[i]) + lo_f(v3[i]));
                    a[2 * i + 1] += (hi_f(v0[i]) + hi_f(v1[i])) + (hi_f(v2[i]) + hi_f(v3[i]));
                }
            }
            for (; j < end; ++j) {
                int c0 = cols[j];
#pragma unroll
                for (int i = 0; i < 4; ++i) {
                    u32 v = hp[(size_t)c0 * 64 + m + 16 * i];
                    a[2 * i]     += lo_f(v);
                    a[2 * i + 1] += hi_f(v);
                }
            }
        }
#pragma unroll
        for (int i = 0; i < 4; ++i) {
            u16 p[2] = { f2b(a[2 * i]), f2b(a[2 * i + 1]) };
            ldsA[nid * ROWSTRIDE + m + 16 * i] = *(u32*)p;
        }
    }

    // B fragments (loaded in the gather's latency shadow)
    short8 B1f0[4], B1f1[4], B2f0[4], B2f1[4];
#pragma unroll
    for (int kc = 0; kc < 4; ++kc) {
        B1f0[kc] = *(const short8*)(Wp1 + ((size_t)(kc * 8 + nt0) * 64 + lane) * 8);
        B1f1[kc] = *(const short8*)(Wp1 + ((size_t)(kc * 8 + nt1) * 64 + lane) * 8);
        B2f0[kc] = *(const short8*)(Wp2 + ((size_t)(kc * 8 + nt0) * 64 + lane) * 8);
        B2f1[kc] = *(const short8*)(Wp2 + ((size_t)(kc * 8 + nt1) * 64 + lane) * 8);
    }
    const int cg0 = nt0 * 16 + m, cg1 = nt1 * 16 + m;
    const float b1v0 = bias1[cg0], b1v1 = bias1[cg1];
    const float b2v0 = bias2[cg0], b2v1 = bias2[cg1];
    __syncthreads();

    // ---- GEMM1: z1 = relu(z0 @ W1 + b1) ----
    {
        short8 a0 = *(const short8*)(&ldsA[m * ROWSTRIDE + 0 * 16 + quad * 4]);
        short8 a1 = *(const short8*)(&ldsA[m * ROWSTRIDE + 1 * 16 + quad * 4]);
        short8 a2 = *(const short8*)(&ldsA[m * ROWSTRIDE + 2 * 16 + quad * 4]);
        short8 a3 = *(const short8*)(&ldsA[m * ROWSTRIDE + 3 * 16 + quad * 4]);
        floatx4 acc0 = {0.f, 0.f, 0.f, 0.f};
        floatx4 acc1 = {0.f, 0.f, 0.f, 0.f};
        acc0 = __builtin_amdgcn_mfma_f32_16x16x32_bf16(a0, B1f0[0], acc0, 0, 0, 0);
        acc1 = __builtin_amdgcn_mfma_f32_16x16x32_bf16(a0, B1f1[0], acc1, 0, 0, 0);
        acc0 = __builtin_amdgcn_mfma_f32_16x16x32_bf16(a1, B1f0[1], acc0, 0, 0, 0);
        acc1 = __builtin_amdgcn_mfma_f32_16x16x32_bf16(a1, B1f1[1], acc1, 0, 0, 0);
        acc0 = __builtin_amdgcn_mfma_f32_16x16x32_bf16(a2, B1f0[2], acc0, 0, 0, 0);
        acc1 = __builtin_amdgcn_mfma_f32_16x16x32_bf16(a2, B1f1[2], acc1, 0, 0, 0);
        acc0 = __builtin_amdgcn_mfma_f32_16x16x32_bf16(a3, B1f0[3], acc0, 0, 0, 0);
        acc1 = __builtin_amdgcn_mfma_f32_16x16x32_bf16(a3, B1f1[3], acc1, 0, 0, 0);
        u16* lb = (u16*)ldsB;
#pragma unroll
        for (int i = 0; i < 4; ++i) {
            int rr = quad * 4 + i;
            lb[rr * (ROWSTRIDE * 2) + cg0] = f2b(fmaxf(acc0[i] + b1v0, 0.f));
            lb[rr * (ROWSTRIDE * 2) + cg1] = f2b(fmaxf(acc1[i] + b1v1, 0.f));
        }
        if (tid < 16) dacc[tid] = 0.f;
    }
    __syncthreads();

    // ---- GEMM2: z2 = (relu?)(z1 @ W2 + b2) ----
    {
        short8 a0 = *(const short8*)(&ldsB[m * ROWSTRIDE + 0 * 16 + quad * 4]);
        short8 a1 = *(const short8*)(&ldsB[m * ROWSTRIDE + 1 * 16 + quad * 4]);
        short8 a2 = *(const short8*)(&ldsB[m * ROWSTRIDE + 2 * 16 + quad * 4]);
        short8 a3 = *(const short8*)(&ldsB[m * ROWSTRIDE + 3 * 16 + quad * 4]);
        floatx4 acc0 = {0.f, 0.f, 0.f, 0.f};
        floatx4 acc1 = {0.f, 0.f, 0.f, 0.f};
        acc0 = __builtin_amdgcn_mfma_f32_16x16x32_bf16(a0, B2f0[0], acc0, 0, 0, 0);
        acc1 = __builtin_amdgcn_mfma_f32_16x16x32_bf16(a0, B2f1[0], acc1, 0, 0, 0);
        acc0 = __builtin_amdgcn_mfma_f32_16x16x32_bf16(a1, B2f0[1], acc0, 0, 0, 0);
        acc1 = __builtin_amdgcn_mfma_f32_16x16x32_bf16(a1, B2f1[1], acc1, 0, 0, 0);
        acc0 = __builtin_amdgcn_mfma_f32_16x16x32_bf16(a2, B2f0[2], acc0, 0, 0, 0);
        acc1 = __builtin_amdgcn_mfma_f32_16x16x32_bf16(a2, B2f1[2], acc1, 0, 0, 0);
        acc0 = __builtin_amdgcn_mfma_f32_16x16x32_bf16(a3, B2f0[3], acc0, 0, 0, 0);
        acc1 = __builtin_amdgcn_mfma_f32_16x16x32_bf16(a3, B2f1[3], acc1, 0, 0, 0);

        if (!lastLayer) {
            u16* la = (u16*)ldsA;
#pragma unroll
            for (int i = 0; i < 4; ++i) {
                int rr = quad * 4 + i;
                float v0 = acc0[i] + b2v0;
                float v1 = acc1[i] + b2v1;
                if (relu2) { v0 = fmaxf(v0, 0.f); v1 = fmaxf(v1, 0.f); }
                la[rr * (ROWSTRIDE * 2) + cg0] = f2b(v0);
                la[rr * (ROWSTRIDE * 2) + cg1] = f2b(v1);
            }
            __syncthreads();
            // coalesced store: each thread copies 16B
            int rr = tid >> 4;
            int s  = tid & 15;
            int grow = row0 + rr;
            if (grow < N) {
                uint4 v = *(uint4*)(&ldsA[rr * ROWSTRIDE + s * 4]);
                *(uint4*)(hout + (size_t)grow * H + s * 8) = v;
            }
        } else {
            // fused head: y[row] = sum_c bf16(z2[row][c]) * Wh[c]
            const float wh0 = Wh[cg0], wh1 = Wh[cg1];
            float part[4];
#pragma unroll
            for (int i = 0; i < 4; ++i)
                part[i] = b2f(f2b(acc0[i] + b2v0)) * wh0 +
                          b2f(f2b(acc1[i] + b2v1)) * wh1;
            // reduce across the 16 lanes of each quad group (xor masks < 16 stay in-group)
#pragma unroll
            for (int off = 1; off < 16; off <<= 1)
#pragma unroll
                for (int i = 0; i < 4; ++i) part[i] += __shfl_xor(part[i], off, 64);
            if (m == 0) {
#pragma unroll
                for (int i = 0; i < 4; ++i) atomicAdd(&dacc[quad * 4 + i], part[i]);
            }
            __syncthreads();
            if (tid < 16 && row0 + tid < N) y[row0 + tid] = dacc[tid];
        }
    }
}

// ------------------------- per-graph mean via binary search on sorted batch -------------------------
__device__ __forceinline__ int lbound(const int* __restrict__ a, int n, int v) {
    int lo = 0, hi = n;
    while (lo < hi) { int mid = (lo + hi) >> 1; if (a[mid] < v) lo = mid + 1; else hi = mid; }
    return lo;
}

__global__ void seg_out_kernel(const float* __restrict__ y, const int* __restrict__ batch,
                               const float* __restrict__ bh, float* __restrict__ out, int N) {
    __shared__ float sh[256];
    int g = blockIdx.x;
    int lo = lbound(batch, N, g);
    int hi = lbound(batch, N, g + 1);
    float s = 0.f;
    for (int i = lo + threadIdx.x; i < hi; i += 256) s += y[i];
    sh[threadIdx.x] = s;
    __syncthreads();
    for (int off = 128; off > 0; off >>= 1) {
        if (threadIdx.x < off) sh[threadIdx.x] += sh[threadIdx.x + off];
        __syncthreads();
    }
    if (threadIdx.x == 0) {
        float cnt = (float)(hi - lo);
        out[g] = sh[0] / fmaxf(cnt, 1.0f) + bh[0];
    }
}

// ------------------------- launch -------------------------
extern "C" void kernel_launch(void* const* d_in, const int* in_sizes, int n_in,
                              void* d_out, int out_size, void* d_ws, size_t ws_size,
                              hipStream_t stream) {
    const float* x    = (const float*)d_in[0];
    const int*   eidx = (const int*)d_in[1];
    const int*   batch= (const int*)d_in[2];
    const float* W1   = (const float*)d_in[3];
    const float* b1   = (const float*)d_in[4];
    const float* W2   = (const float*)d_in[5];
    const float* b2   = (const float*)d_in[6];
    const float* eps  = (const float*)d_in[7];
    const float* Wh   = (const float*)d_in[8];
    const float* bh   = (const float*)d_in[9];

    const int N = in_sizes[0] / H;   // 50000
    const int E = in_sizes[1] / 2;   // 800000
    const int L = in_sizes[7];       // 3
    const int* src  = eidx;
    const int* dstv = eidx + E;
    float* out = (float*)d_out;

    const int NB = (N + NPB - 1) / NPB;   // 196 (<= 256 required)

    char* w = (char*)d_ws;
    u16* B0 = (u16*)w; w += (size_t)N * H * sizeof(u16);
    u16* B1 = (u16*)w; w += (size_t)N * H * sizeof(u16);
    u16* packedW = (u16*)w; w += (size_t)6 * H * H * sizeof(u16);
    float* y    = (float*)w; w += (size_t)N * sizeof(float);
    int* offs   = (int*)w;   w += (size_t)(N + 1) * sizeof(int);
    int* bcnt   = (int*)w;   w += 256 * sizeof(int);
    int* boffs  = (int*)w;   w += 257 * sizeof(int);
    int* bcursor= (int*)w;   w += 256 * sizeof(int);
    u32* stage  = (u32*)w;   w += (size_t)E * sizeof(u32);
    int* cols   = (int*)w;   w += (size_t)E * sizeof(int);

    hipMemsetAsync(bcnt, 0, 256 * sizeof(int), stream);

    // convert x -> bf16
    {
        int n4 = N * H / 4;
        convert_kernel<<<(n4 + 255) / 256, 256, 0, stream>>>(x, B0, n4);
    }
    // pack weights
    {
        int total = 6 * H * H;
        pack_w_kernel<<<(total + 255) / 256, 256, 0, stream>>>(W1, W2, packedW, total);
    }
    // CSR build (two-level bucket sort; no per-edge global atomics)
    bucket_hist<<<256, 256, 0, stream>>>(dstv, bcnt, E, NB);
    bucket_scan<<<1, 64, 0, stream>>>(bcnt, boffs, bcursor, NB);
    scatter_kernel<<<(E + SCHUNK - 1) / SCHUNK, 256, 0, stream>>>(src, dstv, bcursor, stage, E, NB);
    build_csr<<<NB, 256, 0, stream>>>(stage, boffs, offs, cols, N, NB, E);

    const int numTiles = (N + 15) / 16;   // 3125 -> one block per tile
    u16* bufs[2] = { B0, B1 };
    int cur = 0;
    for (int l = 0; l < L; ++l) {
        int nxt = cur ^ 1;
        int last = (l == L - 1) ? 1 : 0;
        fused_layer<<<numTiles, 256, 0, stream>>>(bufs[cur], bufs[nxt], offs, cols,
                                                  packedW + (size_t)l * H * H,
                                                  packedW + (size_t)(3 + l) * H * H,
                                                  b1 + (size_t)l * H, b2 + (size_t)l * H,
                                                  eps, l, (l < L - 1) ? 1 : 0, last,
                                                  Wh, y, N);
        cur = nxt;
    }

    seg_out_kernel<<<NGRAPH, 256, 0, stream>>>(y, batch, bh, out, N);
}